// Round 1
// baseline (2942.736 us; speedup 1.0000x reference)
//
#include <hip/hip_runtime.h>

#define D 128
#define BN_EPS 1e-5f

// ---------------------------------------------------------------- copy z = x
__global__ void copy_f4(const float4* __restrict__ src, float4* __restrict__ dst, int n4) {
    int i = blockIdx.x * blockDim.x + threadIdx.x;
    if (i < n4) dst[i] = src[i];
}

// ------------------------------------------------- z[dst] += x[src] per edge
// 32 lanes per edge, 4 floats per lane.
__global__ void scatter_add(const float* __restrict__ x, const int* __restrict__ src,
                            const int* __restrict__ dst, float* __restrict__ z, int E) {
    int t = blockIdx.x * blockDim.x + threadIdx.x;
    int e = t >> 5;
    if (e >= E) return;
    int lane = t & 31;
    int s = src[e];
    int d = dst[e];
    const float4 v = *reinterpret_cast<const float4*>(x + (size_t)s * D + lane * 4);
    float* zp = z + (size_t)d * D + lane * 4;
    atomicAdd(zp + 0, v.x);
    atomicAdd(zp + 1, v.y);
    atomicAdd(zp + 2, v.z);
    atomicAdd(zp + 3, v.w);
}

// ---------------------------------------------------- GEMM1: out = relu(A@W + b)
// Block: 256 threads, 64 rows. W (128x128) + A-tile (64x128, padded) in LDS.
// Thread (rg = tid>>5, cg = tid&31) computes rows rg*8..rg*8+7, cols cg*4..cg*4+3.
__global__ __launch_bounds__(256) void gemm1_relu(
        const float* __restrict__ A, const float* __restrict__ W,
        const float* __restrict__ b, float* __restrict__ out, int N) {
    __shared__ float sW[D * D];
    __shared__ float sB[D];
    __shared__ float sZ[64 * 132];

    const int tid = threadIdx.x;
    const int row0 = blockIdx.x * 64;

    {
        const float4* W4 = reinterpret_cast<const float4*>(W);
        float4* sW4 = reinterpret_cast<float4*>(sW);
        #pragma unroll
        for (int i = 0; i < 16; i++) sW4[tid + i * 256] = W4[tid + i * 256];
    }
    if (tid < D) sB[tid] = b[tid];
    #pragma unroll
    for (int j = 0; j < 8; j++) {
        int i = tid + j * 256;               // 0..2047 float4 slots
        int r = i >> 5, c4 = i & 31;
        int row = row0 + r;
        float4 v = make_float4(0.f, 0.f, 0.f, 0.f);
        if (row < N) v = *reinterpret_cast<const float4*>(A + (size_t)row * D + c4 * 4);
        *reinterpret_cast<float4*>(&sZ[r * 132 + c4 * 4]) = v;
    }
    __syncthreads();

    const int rg = tid >> 5, cg = tid & 31;
    const int c0 = cg * 4;
    float acc[8][4];
    #pragma unroll
    for (int i = 0; i < 8; i++) {
        acc[i][0] = sB[c0 + 0]; acc[i][1] = sB[c0 + 1];
        acc[i][2] = sB[c0 + 2]; acc[i][3] = sB[c0 + 3];
    }
    const float* zrow = &sZ[(rg * 8) * 132];
    for (int k = 0; k < D; k++) {
        float4 w = *reinterpret_cast<const float4*>(&sW[k * D + c0]);
        #pragma unroll
        for (int i = 0; i < 8; i++) {
            float a = zrow[i * 132 + k];
            acc[i][0] += a * w.x; acc[i][1] += a * w.y;
            acc[i][2] += a * w.z; acc[i][3] += a * w.w;
        }
    }
    #pragma unroll
    for (int i = 0; i < 8; i++) {
        int row = row0 + rg * 8 + i;
        if (row < N) {
            float4 o;
            o.x = fmaxf(acc[i][0], 0.f); o.y = fmaxf(acc[i][1], 0.f);
            o.z = fmaxf(acc[i][2], 0.f); o.w = fmaxf(acc[i][3], 0.f);
            *reinterpret_cast<float4*>(out + (size_t)row * D + c0) = o;
        }
    }
}

// ------------------------- GEMM2: y = A@W + b, plus per-column sum / sumsq stats
__global__ __launch_bounds__(256) void gemm2_stats(
        const float* __restrict__ A, const float* __restrict__ W,
        const float* __restrict__ b, float* __restrict__ out,
        float* __restrict__ gstats, int N) {
    __shared__ float sW[D * D];
    __shared__ float sB[D];
    __shared__ float sZ[64 * 132];
    __shared__ float sStat[2 * D];

    const int tid = threadIdx.x;
    const int row0 = blockIdx.x * 64;

    if (tid < 2 * D) sStat[tid] = 0.f;
    {
        const float4* W4 = reinterpret_cast<const float4*>(W);
        float4* sW4 = reinterpret_cast<float4*>(sW);
        #pragma unroll
        for (int i = 0; i < 16; i++) sW4[tid + i * 256] = W4[tid + i * 256];
    }
    if (tid < D) sB[tid] = b[tid];
    #pragma unroll
    for (int j = 0; j < 8; j++) {
        int i = tid + j * 256;
        int r = i >> 5, c4 = i & 31;
        int row = row0 + r;
        float4 v = make_float4(0.f, 0.f, 0.f, 0.f);
        if (row < N) v = *reinterpret_cast<const float4*>(A + (size_t)row * D + c4 * 4);
        *reinterpret_cast<float4*>(&sZ[r * 132 + c4 * 4]) = v;
    }
    __syncthreads();

    const int rg = tid >> 5, cg = tid & 31;
    const int c0 = cg * 4;
    float acc[8][4];
    #pragma unroll
    for (int i = 0; i < 8; i++) {
        acc[i][0] = sB[c0 + 0]; acc[i][1] = sB[c0 + 1];
        acc[i][2] = sB[c0 + 2]; acc[i][3] = sB[c0 + 3];
    }
    const float* zrow = &sZ[(rg * 8) * 132];
    for (int k = 0; k < D; k++) {
        float4 w = *reinterpret_cast<const float4*>(&sW[k * D + c0]);
        #pragma unroll
        for (int i = 0; i < 8; i++) {
            float a = zrow[i * 132 + k];
            acc[i][0] += a * w.x; acc[i][1] += a * w.y;
            acc[i][2] += a * w.z; acc[i][3] += a * w.w;
        }
    }
    float s[4] = {0.f, 0.f, 0.f, 0.f};
    float sq[4] = {0.f, 0.f, 0.f, 0.f};
    #pragma unroll
    for (int i = 0; i < 8; i++) {
        int row = row0 + rg * 8 + i;
        if (row < N) {
            float4 o;
            o.x = acc[i][0]; o.y = acc[i][1]; o.z = acc[i][2]; o.w = acc[i][3];
            *reinterpret_cast<float4*>(out + (size_t)row * D + c0) = o;
            #pragma unroll
            for (int j = 0; j < 4; j++) {
                s[j]  += acc[i][j];
                sq[j] += acc[i][j] * acc[i][j];
            }
        }
    }
    #pragma unroll
    for (int j = 0; j < 4; j++) {
        atomicAdd(&sStat[c0 + j], s[j]);
        atomicAdd(&sStat[D + c0 + j], sq[j]);
    }
    __syncthreads();
    if (tid < 2 * D) atomicAdd(&gstats[tid], sStat[tid]);
}

// -------------------------------------- BN (training stats) + ReLU, in place
__global__ void bn_relu(float* __restrict__ y, const float* __restrict__ stats,
                        const float* __restrict__ gamma, const float* __restrict__ beta,
                        int N) {
    int i = blockIdx.x * blockDim.x + threadIdx.x;
    int n4 = N * D / 4;
    if (i >= n4) return;
    int c0 = (i << 2) & (D - 1);
    float4 v = reinterpret_cast<float4*>(y)[i];
    float o[4] = {v.x, v.y, v.z, v.w};
    float invN = 1.0f / (float)N;
    #pragma unroll
    for (int j = 0; j < 4; j++) {
        int c = c0 + j;
        float mean = stats[c] * invN;
        float var  = stats[D + c] * invN - mean * mean;
        float sc = rsqrtf(var + BN_EPS) * gamma[c];
        float t = (o[j] - mean) * sc + beta[c];
        o[j] = fmaxf(t, 0.f);
    }
    float4 r; r.x = o[0]; r.y = o[1]; r.z = o[2]; r.w = o[3];
    reinterpret_cast<float4*>(y)[i] = r;
}

extern "C" void kernel_launch(void* const* d_in, const int* in_sizes, int n_in,
                              void* d_out, int out_size, void* d_ws, size_t ws_size,
                              hipStream_t stream) {
    const float* h     = (const float*)d_in[0];
    const int*   ei    = (const int*)d_in[1];
    const float* W1    = (const float*)d_in[2];
    const float* b1    = (const float*)d_in[3];
    const float* W2    = (const float*)d_in[4];
    const float* b2    = (const float*)d_in[5];
    const float* gamma = (const float*)d_in[6];
    const float* beta  = (const float*)d_in[7];
    float* out = (float*)d_out;

    const int N = in_sizes[0] / D;
    const int E = in_sizes[1] / 2;
    const int L = in_sizes[2] / (D * D);

    float* z     = (float*)d_ws;                 // N*D floats
    float* stats = z + (size_t)N * D;            // 2*D floats

    const int n4 = N * D / 4;
    const int copyBlocks = (n4 + 255) / 256;
    const long long scatterThreads = (long long)E * 32;
    const int scatterBlocks = (int)((scatterThreads + 255) / 256);
    const int gemmBlocks = (N + 63) / 64;

    for (int l = 0; l < L; l++) {
        const float* x = (l == 0) ? h : out + (size_t)(l - 1) * N * D;
        float* y = out + (size_t)l * N * D;

        copy_f4<<<copyBlocks, 256, 0, stream>>>((const float4*)x, (float4*)z, n4);
        scatter_add<<<scatterBlocks, 256, 0, stream>>>(x, ei, ei + E, z, E);
        gemm1_relu<<<gemmBlocks, 256, 0, stream>>>(z, W1 + (size_t)l * D * D, b1 + (size_t)l * D, z, N);
        hipMemsetAsync(stats, 0, 2 * D * sizeof(float), stream);
        gemm2_stats<<<gemmBlocks, 256, 0, stream>>>(z, W2 + (size_t)l * D * D, b2 + (size_t)l * D,
                                                    y, stats, N);
        bn_relu<<<copyBlocks, 256, 0, stream>>>(y, stats, gamma + (size_t)l * D, beta + (size_t)l * D, N);
    }
}

// Round 2
// 684.657 us; speedup vs baseline: 4.2981x; 4.2981x over previous
//
#include <hip/hip_runtime.h>

#define D 128
#define BN_EPS 1e-5f

// -------------------------------------------------- CSR build: histogram
__global__ void hist_dst(const int* __restrict__ dst, int* __restrict__ cnt, int E) {
    int e = blockIdx.x * blockDim.x + threadIdx.x;
    if (e < E) atomicAdd(&cnt[dst[e]], 1);
}

// -------------------------------------------------- exclusive scan (1 block)
__global__ void exscan(const int* __restrict__ cnt, int* __restrict__ off, int n) {
    __shared__ int s[256];
    __shared__ int carry;
    if (threadIdx.x == 0) carry = 0;
    __syncthreads();
    for (int base = 0; base < n; base += 256) {
        int i = base + threadIdx.x;
        int v = (i < n) ? cnt[i] : 0;
        s[threadIdx.x] = v;
        __syncthreads();
        for (int ofs = 1; ofs < 256; ofs <<= 1) {
            int t = (threadIdx.x >= ofs) ? s[threadIdx.x - ofs] : 0;
            __syncthreads();
            s[threadIdx.x] += t;
            __syncthreads();
        }
        if (i < n) off[i] = carry + s[threadIdx.x] - v;   // exclusive
        int total = s[255];
        __syncthreads();
        if (threadIdx.x == 0) carry += total;
        __syncthreads();
    }
    if (threadIdx.x == 0) off[n] = carry;
}

// -------------------------------------------------- CSR fill (cursor = copy of off)
__global__ void fill_csr(const int* __restrict__ src, const int* __restrict__ dst,
                         int* __restrict__ cursor, int* __restrict__ eidx, int E) {
    int e = blockIdx.x * blockDim.x + threadIdx.x;
    if (e >= E) return;
    int d = dst[e];
    int pos = atomicAdd(&cursor[d], 1);
    eidx[pos] = src[e];
}

// ------------------------------------ z_i = x_i + sum_{j in N(i)} x_j (gather)
// 32 lanes per node; lane holds float4 (4 cols).
__global__ __launch_bounds__(256) void gather_sum(
        const float* __restrict__ x, const int* __restrict__ off,
        const int* __restrict__ eidx, float* __restrict__ z, int N) {
    int t = blockIdx.x * blockDim.x + threadIdx.x;
    int node = t >> 5;
    if (node >= N) return;
    int lane = t & 31;
    int beg = off[node], end = off[node + 1];
    float4 acc = *reinterpret_cast<const float4*>(x + (size_t)node * D + lane * 4);
    for (int e = beg; e < end; e++) {
        int s = eidx[e];
        const float4 v = *reinterpret_cast<const float4*>(x + (size_t)s * D + lane * 4);
        acc.x += v.x; acc.y += v.y; acc.z += v.z; acc.w += v.w;
    }
    *reinterpret_cast<float4*>(z + (size_t)node * D + lane * 4) = acc;
}

// ---------------------------------------------------- GEMM1: out = relu(A@W + b)
__global__ __launch_bounds__(256) void gemm1_relu(
        const float* __restrict__ A, const float* __restrict__ W,
        const float* __restrict__ b, float* __restrict__ out, int N) {
    __shared__ float sW[D * D];
    __shared__ float sB[D];
    __shared__ float sZ[64 * 132];

    const int tid = threadIdx.x;
    const int row0 = blockIdx.x * 64;

    {
        const float4* W4 = reinterpret_cast<const float4*>(W);
        float4* sW4 = reinterpret_cast<float4*>(sW);
        #pragma unroll
        for (int i = 0; i < 16; i++) sW4[tid + i * 256] = W4[tid + i * 256];
    }
    if (tid < D) sB[tid] = b[tid];
    #pragma unroll
    for (int j = 0; j < 8; j++) {
        int i = tid + j * 256;
        int r = i >> 5, c4 = i & 31;
        int row = row0 + r;
        float4 v = make_float4(0.f, 0.f, 0.f, 0.f);
        if (row < N) v = *reinterpret_cast<const float4*>(A + (size_t)row * D + c4 * 4);
        *reinterpret_cast<float4*>(&sZ[r * 132 + c4 * 4]) = v;
    }
    __syncthreads();

    const int rg = tid >> 5, cg = tid & 31;
    const int c0 = cg * 4;
    float acc[8][4];
    #pragma unroll
    for (int i = 0; i < 8; i++) {
        acc[i][0] = sB[c0 + 0]; acc[i][1] = sB[c0 + 1];
        acc[i][2] = sB[c0 + 2]; acc[i][3] = sB[c0 + 3];
    }
    const float* zrow = &sZ[(rg * 8) * 132];
    for (int k = 0; k < D; k++) {
        float4 w = *reinterpret_cast<const float4*>(&sW[k * D + c0]);
        #pragma unroll
        for (int i = 0; i < 8; i++) {
            float a = zrow[i * 132 + k];
            acc[i][0] += a * w.x; acc[i][1] += a * w.y;
            acc[i][2] += a * w.z; acc[i][3] += a * w.w;
        }
    }
    #pragma unroll
    for (int i = 0; i < 8; i++) {
        int row = row0 + rg * 8 + i;
        if (row < N) {
            float4 o;
            o.x = fmaxf(acc[i][0], 0.f); o.y = fmaxf(acc[i][1], 0.f);
            o.z = fmaxf(acc[i][2], 0.f); o.w = fmaxf(acc[i][3], 0.f);
            *reinterpret_cast<float4*>(out + (size_t)row * D + c0) = o;
        }
    }
}

// ------------------------- GEMM2: y = A@W + b, plus per-column sum / sumsq stats
__global__ __launch_bounds__(256) void gemm2_stats(
        const float* __restrict__ A, const float* __restrict__ W,
        const float* __restrict__ b, float* __restrict__ out,
        float* __restrict__ gstats, int N) {
    __shared__ float sW[D * D];
    __shared__ float sB[D];
    __shared__ float sZ[64 * 132];
    __shared__ float sStat[2 * D];

    const int tid = threadIdx.x;
    const int row0 = blockIdx.x * 64;

    if (tid < 2 * D) sStat[tid] = 0.f;
    {
        const float4* W4 = reinterpret_cast<const float4*>(W);
        float4* sW4 = reinterpret_cast<float4*>(sW);
        #pragma unroll
        for (int i = 0; i < 16; i++) sW4[tid + i * 256] = W4[tid + i * 256];
    }
    if (tid < D) sB[tid] = b[tid];
    #pragma unroll
    for (int j = 0; j < 8; j++) {
        int i = tid + j * 256;
        int r = i >> 5, c4 = i & 31;
        int row = row0 + r;
        float4 v = make_float4(0.f, 0.f, 0.f, 0.f);
        if (row < N) v = *reinterpret_cast<const float4*>(A + (size_t)row * D + c4 * 4);
        *reinterpret_cast<float4*>(&sZ[r * 132 + c4 * 4]) = v;
    }
    __syncthreads();

    const int rg = tid >> 5, cg = tid & 31;
    const int c0 = cg * 4;
    float acc[8][4];
    #pragma unroll
    for (int i = 0; i < 8; i++) {
        acc[i][0] = sB[c0 + 0]; acc[i][1] = sB[c0 + 1];
        acc[i][2] = sB[c0 + 2]; acc[i][3] = sB[c0 + 3];
    }
    const float* zrow = &sZ[(rg * 8) * 132];
    for (int k = 0; k < D; k++) {
        float4 w = *reinterpret_cast<const float4*>(&sW[k * D + c0]);
        #pragma unroll
        for (int i = 0; i < 8; i++) {
            float a = zrow[i * 132 + k];
            acc[i][0] += a * w.x; acc[i][1] += a * w.y;
            acc[i][2] += a * w.z; acc[i][3] += a * w.w;
        }
    }
    float s[4] = {0.f, 0.f, 0.f, 0.f};
    float sq[4] = {0.f, 0.f, 0.f, 0.f};
    #pragma unroll
    for (int i = 0; i < 8; i++) {
        int row = row0 + rg * 8 + i;
        if (row < N) {
            float4 o;
            o.x = acc[i][0]; o.y = acc[i][1]; o.z = acc[i][2]; o.w = acc[i][3];
            *reinterpret_cast<float4*>(out + (size_t)row * D + c0) = o;
            #pragma unroll
            for (int j = 0; j < 4; j++) {
                s[j]  += acc[i][j];
                sq[j] += acc[i][j] * acc[i][j];
            }
        }
    }
    #pragma unroll
    for (int j = 0; j < 4; j++) {
        atomicAdd(&sStat[c0 + j], s[j]);
        atomicAdd(&sStat[D + c0 + j], sq[j]);
    }
    __syncthreads();
    if (tid < 2 * D) atomicAdd(&gstats[tid], sStat[tid]);
}

// -------------------------------------- BN (training stats) + ReLU, in place
__global__ void bn_relu(float* __restrict__ y, const float* __restrict__ stats,
                        const float* __restrict__ gamma, const float* __restrict__ beta,
                        int N) {
    int i = blockIdx.x * blockDim.x + threadIdx.x;
    int n4 = N * D / 4;
    if (i >= n4) return;
    int c0 = (i << 2) & (D - 1);
    float4 v = reinterpret_cast<float4*>(y)[i];
    float o[4] = {v.x, v.y, v.z, v.w};
    float invN = 1.0f / (float)N;
    #pragma unroll
    for (int j = 0; j < 4; j++) {
        int c = c0 + j;
        float mean = stats[c] * invN;
        float var  = stats[D + c] * invN - mean * mean;
        float sc = rsqrtf(var + BN_EPS) * gamma[c];
        float t = (o[j] - mean) * sc + beta[c];
        o[j] = fmaxf(t, 0.f);
    }
    float4 r; r.x = o[0]; r.y = o[1]; r.z = o[2]; r.w = o[3];
    reinterpret_cast<float4*>(y)[i] = r;
}

extern "C" void kernel_launch(void* const* d_in, const int* in_sizes, int n_in,
                              void* d_out, int out_size, void* d_ws, size_t ws_size,
                              hipStream_t stream) {
    const float* h     = (const float*)d_in[0];
    const int*   ei    = (const int*)d_in[1];
    const float* W1    = (const float*)d_in[2];
    const float* b1    = (const float*)d_in[3];
    const float* W2    = (const float*)d_in[4];
    const float* b2    = (const float*)d_in[5];
    const float* gamma = (const float*)d_in[6];
    const float* beta  = (const float*)d_in[7];
    float* out = (float*)d_out;

    const int N = in_sizes[0] / D;
    const int E = in_sizes[1] / 2;
    const int L = in_sizes[2] / (D * D);

    // workspace layout
    float* z     = (float*)d_ws;                       // N*D floats
    float* stats = z + (size_t)N * D;                  // 2*D floats
    int*   cnt    = (int*)(stats + 2 * D);             // N ints
    int*   off    = cnt + N;                           // N+1 ints
    int*   cursor = off + N + 1;                       // N ints
    int*   eidx   = cursor + N;                        // E ints

    const int*   src = ei;
    const int*   dst = ei + E;

    const int n4 = N * D / 4;
    const int ewBlocks = (E + 255) / 256;
    const int gatherBlocks = (N * 32 + 255) / 256;
    const int gemmBlocks = (N + 63) / 64;
    const int bnBlocks = (n4 + 255) / 256;

    // ---- CSR build (once per call; depends only on edge_index)
    hipMemsetAsync(cnt, 0, N * sizeof(int), stream);
    hist_dst<<<ewBlocks, 256, 0, stream>>>(dst, cnt, E);
    exscan<<<1, 256, 0, stream>>>(cnt, off, N);
    hipMemcpyAsync(cursor, off, N * sizeof(int), hipMemcpyDeviceToDevice, stream);
    fill_csr<<<ewBlocks, 256, 0, stream>>>(src, dst, cursor, eidx, E);

    for (int l = 0; l < L; l++) {
        const float* x = (l == 0) ? h : out + (size_t)(l - 1) * N * D;
        float* y = out + (size_t)l * N * D;

        gather_sum<<<gatherBlocks, 256, 0, stream>>>(x, off, eidx, z, N);
        gemm1_relu<<<gemmBlocks, 256, 0, stream>>>(z, W1 + (size_t)l * D * D, b1 + (size_t)l * D, z, N);
        hipMemsetAsync(stats, 0, 2 * D * sizeof(float), stream);
        gemm2_stats<<<gemmBlocks, 256, 0, stream>>>(z, W2 + (size_t)l * D * D, b2 + (size_t)l * D,
                                                    y, stats, N);
        bn_relu<<<bnBlocks, 256, 0, stream>>>(y, stats, gamma + (size_t)l * D, beta + (size_t)l * D, N);
    }
}

// Round 3
// 470.974 us; speedup vs baseline: 6.2482x; 1.4537x over previous
//
#include <hip/hip_runtime.h>

#define D 128
#define BN_EPS 1e-5f

// -------------------------------------------------- CSR build: histogram
__global__ void hist_dst(const int* __restrict__ dst, int* __restrict__ cnt, int E) {
    int e = blockIdx.x * blockDim.x + threadIdx.x;
    if (e < E) atomicAdd(&cnt[dst[e]], 1);
}

// -------------------------------------------------- scan phase 1: per-block reduce
__global__ void reduce_cnt(const int* __restrict__ cnt, int* __restrict__ bsum, int n) {
    __shared__ int s[256];
    int tid = threadIdx.x;
    int i = blockIdx.x * 256 + tid;
    s[tid] = (i < n) ? cnt[i] : 0;
    __syncthreads();
    for (int ofs = 128; ofs > 0; ofs >>= 1) {
        if (tid < ofs) s[tid] += s[tid + ofs];
        __syncthreads();
    }
    if (tid == 0) bsum[blockIdx.x] = s[0];
}

// -------------------------------------------------- scan phase 2: scan block sums (1 block)
// nb <= 256 required (N <= 65536).
__global__ void scan_bsums(const int* __restrict__ bsum, int* __restrict__ blockOff,
                           int* __restrict__ offN, int nb) {
    __shared__ int s[256];
    int tid = threadIdx.x;
    int v = (tid < nb) ? bsum[tid] : 0;
    s[tid] = v;
    __syncthreads();
    for (int ofs = 1; ofs < 256; ofs <<= 1) {
        int t = (tid >= ofs) ? s[tid - ofs] : 0;
        __syncthreads();
        s[tid] += t;
        __syncthreads();
    }
    if (tid < nb) blockOff[tid] = s[tid] - v;   // exclusive
    if (tid == nb - 1) *offN = s[tid];          // grand total
}

// -------------------------------------------------- scan phase 3: per-block scan + offset
__global__ void scan_partial(const int* __restrict__ cnt, int* __restrict__ off,
                             int* __restrict__ cursor, const int* __restrict__ blockOff, int n) {
    __shared__ int s[256];
    int tid = threadIdx.x;
    int i = blockIdx.x * 256 + tid;
    int v = (i < n) ? cnt[i] : 0;
    s[tid] = v;
    __syncthreads();
    for (int ofs = 1; ofs < 256; ofs <<= 1) {
        int t = (tid >= ofs) ? s[tid - ofs] : 0;
        __syncthreads();
        s[tid] += t;
        __syncthreads();
    }
    if (i < n) {
        int o = blockOff[blockIdx.x] + s[tid] - v;
        off[i] = o;
        cursor[i] = o;
    }
}

// -------------------------------------------------- CSR fill (cursor = copy of off)
__global__ void fill_csr(const int* __restrict__ src, const int* __restrict__ dst,
                         int* __restrict__ cursor, int* __restrict__ eidx, int E) {
    int e = blockIdx.x * blockDim.x + threadIdx.x;
    if (e >= E) return;
    int d = dst[e];
    int pos = atomicAdd(&cursor[d], 1);
    eidx[pos] = src[e];
}

// ------------------------------------ z_i = x_i + sum_{j in N(i)} x_j (gather)
__global__ __launch_bounds__(256) void gather_sum(
        const float* __restrict__ x, const int* __restrict__ off,
        const int* __restrict__ eidx, float* __restrict__ z, int N) {
    int t = blockIdx.x * blockDim.x + threadIdx.x;
    int node = t >> 5;
    if (node >= N) return;
    int lane = t & 31;
    int beg = off[node], end = off[node + 1];
    float4 acc = *reinterpret_cast<const float4*>(x + (size_t)node * D + lane * 4);
    for (int e = beg; e < end; e++) {
        int s = eidx[e];
        const float4 v = *reinterpret_cast<const float4*>(x + (size_t)s * D + lane * 4);
        acc.x += v.x; acc.y += v.y; acc.z += v.z; acc.w += v.w;
    }
    *reinterpret_cast<float4*>(z + (size_t)node * D + lane * 4) = acc;
}

// ---------------------------------------------------- GEMM1: out = relu(A@W + b)
__global__ __launch_bounds__(256) void gemm1_relu(
        const float* __restrict__ A, const float* __restrict__ W,
        const float* __restrict__ b, float* __restrict__ out, int N) {
    __shared__ float sW[D * D];
    __shared__ float sB[D];
    __shared__ float sZ[64 * 132];

    const int tid = threadIdx.x;
    const int row0 = blockIdx.x * 64;

    {
        const float4* W4 = reinterpret_cast<const float4*>(W);
        float4* sW4 = reinterpret_cast<float4*>(sW);
        #pragma unroll
        for (int i = 0; i < 16; i++) sW4[tid + i * 256] = W4[tid + i * 256];
    }
    if (tid < D) sB[tid] = b[tid];
    #pragma unroll
    for (int j = 0; j < 8; j++) {
        int i = tid + j * 256;
        int r = i >> 5, c4 = i & 31;
        int row = row0 + r;
        float4 v = make_float4(0.f, 0.f, 0.f, 0.f);
        if (row < N) v = *reinterpret_cast<const float4*>(A + (size_t)row * D + c4 * 4);
        *reinterpret_cast<float4*>(&sZ[r * 132 + c4 * 4]) = v;
    }
    __syncthreads();

    const int rg = tid >> 5, cg = tid & 31;
    const int c0 = cg * 4;
    float acc[8][4];
    #pragma unroll
    for (int i = 0; i < 8; i++) {
        acc[i][0] = sB[c0 + 0]; acc[i][1] = sB[c0 + 1];
        acc[i][2] = sB[c0 + 2]; acc[i][3] = sB[c0 + 3];
    }
    const float* zrow = &sZ[(rg * 8) * 132];
    for (int k = 0; k < D; k++) {
        float4 w = *reinterpret_cast<const float4*>(&sW[k * D + c0]);
        #pragma unroll
        for (int i = 0; i < 8; i++) {
            float a = zrow[i * 132 + k];
            acc[i][0] += a * w.x; acc[i][1] += a * w.y;
            acc[i][2] += a * w.z; acc[i][3] += a * w.w;
        }
    }
    #pragma unroll
    for (int i = 0; i < 8; i++) {
        int row = row0 + rg * 8 + i;
        if (row < N) {
            float4 o;
            o.x = fmaxf(acc[i][0], 0.f); o.y = fmaxf(acc[i][1], 0.f);
            o.z = fmaxf(acc[i][2], 0.f); o.w = fmaxf(acc[i][3], 0.f);
            *reinterpret_cast<float4*>(out + (size_t)row * D + c0) = o;
        }
    }
}

// ------------------------- GEMM2: y = A@W + b, plus per-column sum / sumsq stats
__global__ __launch_bounds__(256) void gemm2_stats(
        const float* __restrict__ A, const float* __restrict__ W,
        const float* __restrict__ b, float* __restrict__ out,
        float* __restrict__ gstats, int N) {
    __shared__ float sW[D * D];
    __shared__ float sB[D];
    __shared__ float sZ[64 * 132];
    __shared__ float sStat[2 * D];

    const int tid = threadIdx.x;
    const int row0 = blockIdx.x * 64;

    if (tid < 2 * D) sStat[tid] = 0.f;
    {
        const float4* W4 = reinterpret_cast<const float4*>(W);
        float4* sW4 = reinterpret_cast<float4*>(sW);
        #pragma unroll
        for (int i = 0; i < 16; i++) sW4[tid + i * 256] = W4[tid + i * 256];
    }
    if (tid < D) sB[tid] = b[tid];
    #pragma unroll
    for (int j = 0; j < 8; j++) {
        int i = tid + j * 256;
        int r = i >> 5, c4 = i & 31;
        int row = row0 + r;
        float4 v = make_float4(0.f, 0.f, 0.f, 0.f);
        if (row < N) v = *reinterpret_cast<const float4*>(A + (size_t)row * D + c4 * 4);
        *reinterpret_cast<float4*>(&sZ[r * 132 + c4 * 4]) = v;
    }
    __syncthreads();

    const int rg = tid >> 5, cg = tid & 31;
    const int c0 = cg * 4;
    float acc[8][4];
    #pragma unroll
    for (int i = 0; i < 8; i++) {
        acc[i][0] = sB[c0 + 0]; acc[i][1] = sB[c0 + 1];
        acc[i][2] = sB[c0 + 2]; acc[i][3] = sB[c0 + 3];
    }
    const float* zrow = &sZ[(rg * 8) * 132];
    for (int k = 0; k < D; k++) {
        float4 w = *reinterpret_cast<const float4*>(&sW[k * D + c0]);
        #pragma unroll
        for (int i = 0; i < 8; i++) {
            float a = zrow[i * 132 + k];
            acc[i][0] += a * w.x; acc[i][1] += a * w.y;
            acc[i][2] += a * w.z; acc[i][3] += a * w.w;
        }
    }
    float s[4] = {0.f, 0.f, 0.f, 0.f};
    float sq[4] = {0.f, 0.f, 0.f, 0.f};
    #pragma unroll
    for (int i = 0; i < 8; i++) {
        int row = row0 + rg * 8 + i;
        if (row < N) {
            float4 o;
            o.x = acc[i][0]; o.y = acc[i][1]; o.z = acc[i][2]; o.w = acc[i][3];
            *reinterpret_cast<float4*>(out + (size_t)row * D + c0) = o;
            #pragma unroll
            for (int j = 0; j < 4; j++) {
                s[j]  += acc[i][j];
                sq[j] += acc[i][j] * acc[i][j];
            }
        }
    }
    #pragma unroll
    for (int j = 0; j < 4; j++) {
        atomicAdd(&sStat[c0 + j], s[j]);
        atomicAdd(&sStat[D + c0 + j], sq[j]);
    }
    __syncthreads();
    if (tid < 2 * D) atomicAdd(&gstats[tid], sStat[tid]);
}

// -------------------------------------- BN (training stats) + ReLU, in place
__global__ void bn_relu(float* __restrict__ y, const float* __restrict__ stats,
                        const float* __restrict__ gamma, const float* __restrict__ beta,
                        int N) {
    int i = blockIdx.x * blockDim.x + threadIdx.x;
    int n4 = N * D / 4;
    if (i >= n4) return;
    int c0 = (i << 2) & (D - 1);
    float4 v = reinterpret_cast<float4*>(y)[i];
    float o[4] = {v.x, v.y, v.z, v.w};
    float invN = 1.0f / (float)N;
    #pragma unroll
    for (int j = 0; j < 4; j++) {
        int c = c0 + j;
        float mean = stats[c] * invN;
        float var  = stats[D + c] * invN - mean * mean;
        float sc = rsqrtf(var + BN_EPS) * gamma[c];
        float t = (o[j] - mean) * sc + beta[c];
        o[j] = fmaxf(t, 0.f);
    }
    float4 r; r.x = o[0]; r.y = o[1]; r.z = o[2]; r.w = o[3];
    reinterpret_cast<float4*>(y)[i] = r;
}

extern "C" void kernel_launch(void* const* d_in, const int* in_sizes, int n_in,
                              void* d_out, int out_size, void* d_ws, size_t ws_size,
                              hipStream_t stream) {
    const float* h     = (const float*)d_in[0];
    const int*   ei    = (const int*)d_in[1];
    const float* W1    = (const float*)d_in[2];
    const float* b1    = (const float*)d_in[3];
    const float* W2    = (const float*)d_in[4];
    const float* b2    = (const float*)d_in[5];
    const float* gamma = (const float*)d_in[6];
    const float* beta  = (const float*)d_in[7];
    float* out = (float*)d_out;

    const int N = in_sizes[0] / D;
    const int E = in_sizes[1] / 2;
    const int L = in_sizes[2] / (D * D);
    const int nb = (N + 255) / 256;   // scan blocks (must be <= 256)

    // workspace layout
    float* z        = (float*)d_ws;                    // N*D floats
    float* stats    = z + (size_t)N * D;               // 2*D floats
    int*   cnt      = (int*)(stats + 2 * D);           // N ints
    int*   off      = cnt + N;                         // N+1 ints
    int*   cursor   = off + N + 1;                     // N ints
    int*   bsum     = cursor + N;                      // nb ints
    int*   blockOff = bsum + nb;                       // nb ints
    int*   eidx     = blockOff + nb;                   // E ints

    const int* src = ei;
    const int* dst = ei + E;

    const int n4 = N * D / 4;
    const int ewBlocks = (E + 255) / 256;
    const int gatherBlocks = (N * 32 + 255) / 256;
    const int gemmBlocks = (N + 63) / 64;
    const int bnBlocks = (n4 + 255) / 256;

    // ---- CSR build
    hipMemsetAsync(cnt, 0, N * sizeof(int), stream);
    hist_dst<<<ewBlocks, 256, 0, stream>>>(dst, cnt, E);
    reduce_cnt<<<nb, 256, 0, stream>>>(cnt, bsum, N);
    scan_bsums<<<1, 256, 0, stream>>>(bsum, blockOff, off + N, nb);
    scan_partial<<<nb, 256, 0, stream>>>(cnt, off, cursor, blockOff, N);
    fill_csr<<<ewBlocks, 256, 0, stream>>>(src, dst, cursor, eidx, E);

    for (int l = 0; l < L; l++) {
        const float* x = (l == 0) ? h : out + (size_t)(l - 1) * N * D;
        float* y = out + (size_t)l * N * D;

        gather_sum<<<gatherBlocks, 256, 0, stream>>>(x, off, eidx, z, N);
        gemm1_relu<<<gemmBlocks, 256, 0, stream>>>(z, W1 + (size_t)l * D * D, b1 + (size_t)l * D, z, N);
        hipMemsetAsync(stats, 0, 2 * D * sizeof(float), stream);
        gemm2_stats<<<gemmBlocks, 256, 0, stream>>>(z, W2 + (size_t)l * D * D, b2 + (size_t)l * D,
                                                    y, stats, N);
        bn_relu<<<bnBlocks, 256, 0, stream>>>(y, stats, gamma + (size_t)l * D, beta + (size_t)l * D, N);
    }
}

// Round 4
// 326.864 us; speedup vs baseline: 9.0029x; 1.4409x over previous
//
#include <hip/hip_runtime.h>

#define D 128
#define BN_EPS 1e-5f

typedef __attribute__((ext_vector_type(8))) short short8;
typedef __attribute__((ext_vector_type(4))) float f32x4;

// float -> bf16 bits, round-to-nearest-even
__device__ inline unsigned short f2bf(float f) {
    union { float f; unsigned int u; } v; v.f = f;
    unsigned int u = v.u;
    unsigned int r = (u + 0x7FFFu + ((u >> 16) & 1u)) >> 16;
    return (unsigned short)r;
}

// -------------------------------------------------- CSR build: histogram
__global__ void hist_dst(const int* __restrict__ dst, int* __restrict__ cnt, int E) {
    int e = blockIdx.x * blockDim.x + threadIdx.x;
    if (e < E) atomicAdd(&cnt[dst[e]], 1);
}

// -------------------------------------------------- scan phase 1: per-block reduce
__global__ void reduce_cnt(const int* __restrict__ cnt, int* __restrict__ bsum, int n) {
    __shared__ int s[256];
    int tid = threadIdx.x;
    int i = blockIdx.x * 256 + tid;
    s[tid] = (i < n) ? cnt[i] : 0;
    __syncthreads();
    for (int ofs = 128; ofs > 0; ofs >>= 1) {
        if (tid < ofs) s[tid] += s[tid + ofs];
        __syncthreads();
    }
    if (tid == 0) bsum[blockIdx.x] = s[0];
}

// -------------------------------------------------- scan phase 2: scan block sums (1 block)
__global__ void scan_bsums(const int* __restrict__ bsum, int* __restrict__ blockOff,
                           int* __restrict__ offN, int nb) {
    __shared__ int s[256];
    int tid = threadIdx.x;
    int v = (tid < nb) ? bsum[tid] : 0;
    s[tid] = v;
    __syncthreads();
    for (int ofs = 1; ofs < 256; ofs <<= 1) {
        int t = (tid >= ofs) ? s[tid - ofs] : 0;
        __syncthreads();
        s[tid] += t;
        __syncthreads();
    }
    if (tid < nb) blockOff[tid] = s[tid] - v;
    if (tid == nb - 1) *offN = s[tid];
}

// -------------------------------------------------- scan phase 3: per-block scan + offset
__global__ void scan_partial(const int* __restrict__ cnt, int* __restrict__ off,
                             int* __restrict__ cursor, const int* __restrict__ blockOff, int n) {
    __shared__ int s[256];
    int tid = threadIdx.x;
    int i = blockIdx.x * 256 + tid;
    int v = (i < n) ? cnt[i] : 0;
    s[tid] = v;
    __syncthreads();
    for (int ofs = 1; ofs < 256; ofs <<= 1) {
        int t = (tid >= ofs) ? s[tid - ofs] : 0;
        __syncthreads();
        s[tid] += t;
        __syncthreads();
    }
    if (i < n) {
        int o = blockOff[blockIdx.x] + s[tid] - v;
        off[i] = o;
        cursor[i] = o;
    }
}

// -------------------------------------------------- CSR fill
__global__ void fill_csr(const int* __restrict__ src, const int* __restrict__ dst,
                         int* __restrict__ cursor, int* __restrict__ eidx, int E) {
    int e = blockIdx.x * blockDim.x + threadIdx.x;
    if (e >= E) return;
    int d = dst[e];
    int pos = atomicAdd(&cursor[d], 1);
    eidx[pos] = src[e];
}

// ------------------------- weight prep: Wt[m][n][k] = bf16(W[m][k][n]), m = 2L mats
__global__ void wprep(const float* __restrict__ W1, const float* __restrict__ W2,
                      unsigned short* __restrict__ Wt, int L) {
    int idx = blockIdx.x * 256 + threadIdx.x;     // over 2*L*16384
    int m = idx >> 14;
    int rem = idx & 16383;
    int c = rem >> 7, k = rem & 127;
    const float* W = (m < L) ? (W1 + (size_t)m * D * D) : (W2 + (size_t)(m - L) * D * D);
    Wt[(size_t)m * D * D + c * D + k] = f2bf(W[k * D + c]);
}

// ------------------------------------ z_i = x_i + sum_{j in N(i)} x_j -> bf16
__global__ __launch_bounds__(256) void gather_sum_bf16(
        const float* __restrict__ x, const int* __restrict__ off,
        const int* __restrict__ eidx, unsigned short* __restrict__ zb, int N) {
    int t = blockIdx.x * blockDim.x + threadIdx.x;
    int node = t >> 5;
    if (node >= N) return;
    int lane = t & 31;
    int beg = off[node], end = off[node + 1];
    float4 acc = *reinterpret_cast<const float4*>(x + (size_t)node * D + lane * 4);
    for (int e = beg; e < end; e++) {
        int s = eidx[e];
        const float4 v = *reinterpret_cast<const float4*>(x + (size_t)s * D + lane * 4);
        acc.x += v.x; acc.y += v.y; acc.z += v.z; acc.w += v.w;
    }
    uint2 o;
    o.x = (unsigned)f2bf(acc.x) | ((unsigned)f2bf(acc.y) << 16);
    o.y = (unsigned)f2bf(acc.z) | ((unsigned)f2bf(acc.w) << 16);
    *reinterpret_cast<uint2*>(zb + (size_t)node * D + lane * 4) = o;
}

// ---------------------------------------------------- MFMA GEMM1: zb = relu(zb@W1 + b1) (bf16 out, in-place safe)
__global__ __launch_bounds__(256) void gemm1_mfma(
        const unsigned short* __restrict__ A, const unsigned short* __restrict__ Wt,
        const float* __restrict__ bias, unsigned short* __restrict__ Out, int N) {
    __shared__ __align__(16) char sW[32768];
    const int tid = threadIdx.x;
    // stage Wt (bf16, [n][k] 128x128) into LDS, XOR-swizzled 16B slots
    #pragma unroll
    for (int it = 0; it < 8; it++) {
        int idx = tid + it * 256;                 // 16B chunk id, 2048 total
        int row = idx >> 4, slot = idx & 15;
        uint4 v = *reinterpret_cast<const uint4*>(Wt + ((size_t)idx << 3));
        *reinterpret_cast<uint4*>(sW + row * 256 + ((slot * 16) ^ ((row & 7) << 4))) = v;
    }
    __syncthreads();

    const int lane = tid & 63, wv = tid >> 6;
    const int r0 = blockIdx.x * 64 + wv * 16;
    int arow = r0 + (lane & 15); if (arow >= N) arow = N - 1;
    const unsigned short* aptr = A + (size_t)arow * D + ((lane >> 4) << 3);

    f32x4 acc[8];
    #pragma unroll
    for (int ct = 0; ct < 8; ct++) {
        float b = bias[ct * 16 + (lane & 15)];
        acc[ct] = (f32x4){b, b, b, b};
    }
    #pragma unroll
    for (int ks = 0; ks < 4; ks++) {
        short8 a = *reinterpret_cast<const short8*>(aptr + ks * 32);
        #pragma unroll
        for (int ct = 0; ct < 8; ct++) {
            int rr = ct * 16 + (lane & 15);
            int kb = ks * 64 + ((lane >> 4) << 4);
            short8 bfr = *reinterpret_cast<const short8*>(sW + rr * 256 + (kb ^ ((rr & 7) << 4)));
            acc[ct] = __builtin_amdgcn_mfma_f32_16x16x32_bf16(a, bfr, acc[ct], 0, 0, 0);
        }
    }
    #pragma unroll
    for (int ct = 0; ct < 8; ct++) {
        #pragma unroll
        for (int r = 0; r < 4; r++) {
            int row = r0 + ((lane >> 4) << 2) + r;
            if (row < N)
                Out[(size_t)row * D + ct * 16 + (lane & 15)] = f2bf(fmaxf(acc[ct][r], 0.f));
        }
    }
}

// ----------------------- MFMA GEMM2: y = zb@W2 + b2 (fp32 out) + column stats
__global__ __launch_bounds__(256) void gemm2_mfma(
        const unsigned short* __restrict__ A, const unsigned short* __restrict__ Wt,
        const float* __restrict__ bias, float* __restrict__ Out,
        float* __restrict__ gstats, int N) {
    __shared__ __align__(16) char sW[32768];
    __shared__ float sStat[2 * D];
    const int tid = threadIdx.x;
    if (tid < 2 * D) sStat[tid] = 0.f;
    #pragma unroll
    for (int it = 0; it < 8; it++) {
        int idx = tid + it * 256;
        int row = idx >> 4, slot = idx & 15;
        uint4 v = *reinterpret_cast<const uint4*>(Wt + ((size_t)idx << 3));
        *reinterpret_cast<uint4*>(sW + row * 256 + ((slot * 16) ^ ((row & 7) << 4))) = v;
    }
    __syncthreads();

    const int lane = tid & 63, wv = tid >> 6;
    const int r0 = blockIdx.x * 64 + wv * 16;
    int arow = r0 + (lane & 15); if (arow >= N) arow = N - 1;
    const unsigned short* aptr = A + (size_t)arow * D + ((lane >> 4) << 3);

    f32x4 acc[8];
    #pragma unroll
    for (int ct = 0; ct < 8; ct++) {
        float b = bias[ct * 16 + (lane & 15)];
        acc[ct] = (f32x4){b, b, b, b};
    }
    #pragma unroll
    for (int ks = 0; ks < 4; ks++) {
        short8 a = *reinterpret_cast<const short8*>(aptr + ks * 32);
        #pragma unroll
        for (int ct = 0; ct < 8; ct++) {
            int rr = ct * 16 + (lane & 15);
            int kb = ks * 64 + ((lane >> 4) << 4);
            short8 bfr = *reinterpret_cast<const short8*>(sW + rr * 256 + (kb ^ ((rr & 7) << 4)));
            acc[ct] = __builtin_amdgcn_mfma_f32_16x16x32_bf16(a, bfr, acc[ct], 0, 0, 0);
        }
    }
    #pragma unroll
    for (int ct = 0; ct < 8; ct++) {
        float s = 0.f, q = 0.f;
        #pragma unroll
        for (int r = 0; r < 4; r++) {
            int row = r0 + ((lane >> 4) << 2) + r;
            float v = acc[ct][r];
            if (row < N) {
                Out[(size_t)row * D + ct * 16 + (lane & 15)] = v;
                s += v; q += v * v;
            }
        }
        s += __shfl_xor(s, 16); q += __shfl_xor(q, 16);
        s += __shfl_xor(s, 32); q += __shfl_xor(q, 32);
        if (lane < 16) {
            atomicAdd(&sStat[ct * 16 + lane], s);
            atomicAdd(&sStat[D + ct * 16 + lane], q);
        }
    }
    __syncthreads();
    if (tid < 2 * D) atomicAdd(&gstats[tid], sStat[tid]);
}

// -------------------------------------- BN (training stats) + ReLU, in place
__global__ void bn_relu(float* __restrict__ y, const float* __restrict__ stats,
                        const float* __restrict__ gamma, const float* __restrict__ beta,
                        int N) {
    int i = blockIdx.x * blockDim.x + threadIdx.x;
    int n4 = N * D / 4;
    if (i >= n4) return;
    int c0 = (i << 2) & (D - 1);
    float4 v = reinterpret_cast<float4*>(y)[i];
    float o[4] = {v.x, v.y, v.z, v.w};
    float invN = 1.0f / (float)N;
    #pragma unroll
    for (int j = 0; j < 4; j++) {
        int c = c0 + j;
        float mean = stats[c] * invN;
        float var  = stats[D + c] * invN - mean * mean;
        float sc = rsqrtf(var + BN_EPS) * gamma[c];
        float t = (o[j] - mean) * sc + beta[c];
        o[j] = fmaxf(t, 0.f);
    }
    float4 r; r.x = o[0]; r.y = o[1]; r.z = o[2]; r.w = o[3];
    reinterpret_cast<float4*>(y)[i] = r;
}

extern "C" void kernel_launch(void* const* d_in, const int* in_sizes, int n_in,
                              void* d_out, int out_size, void* d_ws, size_t ws_size,
                              hipStream_t stream) {
    const float* h     = (const float*)d_in[0];
    const int*   ei    = (const int*)d_in[1];
    const float* W1    = (const float*)d_in[2];
    const float* b1    = (const float*)d_in[3];
    const float* W2    = (const float*)d_in[4];
    const float* b2    = (const float*)d_in[5];
    const float* gamma = (const float*)d_in[6];
    const float* beta  = (const float*)d_in[7];
    float* out = (float*)d_out;

    const int N = in_sizes[0] / D;
    const int E = in_sizes[1] / 2;
    const int L = in_sizes[2] / (D * D);
    const int nb = (N + 255) / 256;

    // workspace layout (16B alignment holds: N*D*2 is a multiple of 16)
    unsigned short* zb   = (unsigned short*)d_ws;            // N*D bf16
    unsigned short* Wt   = zb + (size_t)N * D;               // 2L*128*128 bf16
    float*          stats = (float*)(Wt + (size_t)2 * L * D * D); // L*2*D floats
    int* cnt      = (int*)(stats + (size_t)L * 2 * D);
    int* off      = cnt + N;
    int* cursor   = off + N + 1;
    int* bsum     = cursor + N;
    int* blockOff = bsum + nb;
    int* eidx     = blockOff + nb;

    const int* src = ei;
    const int* dst = ei + E;

    const int n4 = N * D / 4;
    const int ewBlocks = (E + 255) / 256;
    const int gatherBlocks = (N * 32 + 255) / 256;
    const int gemmBlocks = (N + 63) / 64;
    const int bnBlocks = (n4 + 255) / 256;
    const int wprepBlocks = (2 * L * D * D) / 256;

    hipMemsetAsync(cnt, 0, N * sizeof(int), stream);
    hipMemsetAsync(stats, 0, (size_t)L * 2 * D * sizeof(float), stream);
    wprep<<<wprepBlocks, 256, 0, stream>>>(W1, W2, Wt, L);

    // ---- CSR build
    hist_dst<<<ewBlocks, 256, 0, stream>>>(dst, cnt, E);
    reduce_cnt<<<nb, 256, 0, stream>>>(cnt, bsum, N);
    scan_bsums<<<1, 256, 0, stream>>>(bsum, blockOff, off + N, nb);
    scan_partial<<<nb, 256, 0, stream>>>(cnt, off, cursor, blockOff, N);
    fill_csr<<<ewBlocks, 256, 0, stream>>>(src, dst, cursor, eidx, E);

    for (int l = 0; l < L; l++) {
        const float* x = (l == 0) ? h : out + (size_t)(l - 1) * N * D;
        float* y = out + (size_t)l * N * D;

        gather_sum_bf16<<<gatherBlocks, 256, 0, stream>>>(x, off, eidx, zb, N);
        gemm1_mfma<<<gemmBlocks, 256, 0, stream>>>(zb, Wt + (size_t)l * D * D,
                                                   b1 + (size_t)l * D, zb, N);
        gemm2_mfma<<<gemmBlocks, 256, 0, stream>>>(zb, Wt + (size_t)(L + l) * D * D,
                                                   b2 + (size_t)l * D, y, stats + (size_t)l * 2 * D, N);
        bn_relu<<<bnBlocks, 256, 0, stream>>>(y, stats + (size_t)l * 2 * D,
                                              gamma + (size_t)l * D, beta + (size_t)l * D, N);
    }
}

// Round 5
// 276.459 us; speedup vs baseline: 10.6444x; 1.1823x over previous
//
#include <hip/hip_runtime.h>

#define D 128
#define BN_EPS 1e-5f

typedef __attribute__((ext_vector_type(8))) short short8;
typedef __attribute__((ext_vector_type(4))) float f32x4;

// float -> bf16 bits, round-to-nearest-even
__device__ inline unsigned short f2bf(float f) {
    union { float f; unsigned int u; } v; v.f = f;
    unsigned int u = v.u;
    unsigned int r = (u + 0x7FFFu + ((u >> 16) & 1u)) >> 16;
    return (unsigned short)r;
}

__device__ inline float bfbits2f(unsigned int bits) {
    union { unsigned int u; float f; } v; v.u = bits;
    return v.f;
}

// uint2 holding 4 packed bf16 -> float4
__device__ inline float4 bf2f4(uint2 v) {
    float4 r;
    r.x = bfbits2f(v.x << 16);
    r.y = bfbits2f(v.x & 0xFFFF0000u);
    r.z = bfbits2f(v.y << 16);
    r.w = bfbits2f(v.y & 0xFFFF0000u);
    return r;
}

// -------------------------------------------------- CSR build: histogram
__global__ void hist_dst(const int* __restrict__ dst, int* __restrict__ cnt, int E) {
    int e = blockIdx.x * blockDim.x + threadIdx.x;
    if (e < E) atomicAdd(&cnt[dst[e]], 1);
}

// -------------------------------------------------- scan phase 1: per-block reduce
__global__ void reduce_cnt(const int* __restrict__ cnt, int* __restrict__ bsum, int n) {
    __shared__ int s[256];
    int tid = threadIdx.x;
    int i = blockIdx.x * 256 + tid;
    s[tid] = (i < n) ? cnt[i] : 0;
    __syncthreads();
    for (int ofs = 128; ofs > 0; ofs >>= 1) {
        if (tid < ofs) s[tid] += s[tid + ofs];
        __syncthreads();
    }
    if (tid == 0) bsum[blockIdx.x] = s[0];
}

// -------------------------------------------------- scan phase 2: scan block sums (1 block)
__global__ void scan_bsums(const int* __restrict__ bsum, int* __restrict__ blockOff,
                           int* __restrict__ offN, int nb) {
    __shared__ int s[256];
    int tid = threadIdx.x;
    int v = (tid < nb) ? bsum[tid] : 0;
    s[tid] = v;
    __syncthreads();
    for (int ofs = 1; ofs < 256; ofs <<= 1) {
        int t = (tid >= ofs) ? s[tid - ofs] : 0;
        __syncthreads();
        s[tid] += t;
        __syncthreads();
    }
    if (tid < nb) blockOff[tid] = s[tid] - v;
    if (tid == nb - 1) *offN = s[tid];
}

// -------------------------------------------------- scan phase 3: per-block scan + offset
__global__ void scan_partial(const int* __restrict__ cnt, int* __restrict__ off,
                             int* __restrict__ cursor, const int* __restrict__ blockOff, int n) {
    __shared__ int s[256];
    int tid = threadIdx.x;
    int i = blockIdx.x * 256 + tid;
    int v = (i < n) ? cnt[i] : 0;
    s[tid] = v;
    __syncthreads();
    for (int ofs = 1; ofs < 256; ofs <<= 1) {
        int t = (tid >= ofs) ? s[tid - ofs] : 0;
        __syncthreads();
        s[tid] += t;
        __syncthreads();
    }
    if (i < n) {
        int o = blockOff[blockIdx.x] + s[tid] - v;
        off[i] = o;
        cursor[i] = o;
    }
}

// -------------------------------------------------- CSR fill
__global__ void fill_csr(const int* __restrict__ src, const int* __restrict__ dst,
                         int* __restrict__ cursor, int* __restrict__ eidx, int E) {
    int e = blockIdx.x * blockDim.x + threadIdx.x;
    if (e >= E) return;
    int d = dst[e];
    int pos = atomicAdd(&cursor[d], 1);
    eidx[pos] = src[e];
}

// ------------------------- weight prep: Wt[m][n][k] = bf16(W[m][k][n]), m = 2L mats
__global__ void wprep(const float* __restrict__ W1, const float* __restrict__ W2,
                      unsigned short* __restrict__ Wt, int L) {
    int idx = blockIdx.x * 256 + threadIdx.x;     // over 2*L*16384
    int m = idx >> 14;
    int rem = idx & 16383;
    int c = rem >> 7, k = rem & 127;
    const float* W = (m < L) ? (W1 + (size_t)m * D * D) : (W2 + (size_t)(m - L) * D * D);
    Wt[(size_t)m * D * D + c * D + k] = f2bf(W[k * D + c]);
}

// -------------------------------------------------- h (fp32) -> xb (bf16), 8 elems/thread
__global__ void x2bf(const float* __restrict__ x, unsigned short* __restrict__ xb, int n8) {
    int i = blockIdx.x * 256 + threadIdx.x;
    if (i >= n8) return;
    float4 a = reinterpret_cast<const float4*>(x)[2 * i];
    float4 b = reinterpret_cast<const float4*>(x)[2 * i + 1];
    uint4 o;
    o.x = (unsigned)f2bf(a.x) | ((unsigned)f2bf(a.y) << 16);
    o.y = (unsigned)f2bf(a.z) | ((unsigned)f2bf(a.w) << 16);
    o.z = (unsigned)f2bf(b.x) | ((unsigned)f2bf(b.y) << 16);
    o.w = (unsigned)f2bf(b.z) | ((unsigned)f2bf(b.w) << 16);
    reinterpret_cast<uint4*>(xb)[i] = o;
}

// ------------------------------ z_i = x_i + sum_{j in N(i)} x_j, bf16 in / bf16 out
__global__ __launch_bounds__(256) void gather_bf(
        const unsigned short* __restrict__ xb, const int* __restrict__ off,
        const int* __restrict__ eidx, unsigned short* __restrict__ zb, int N) {
    int t = blockIdx.x * blockDim.x + threadIdx.x;
    int node = t >> 5;
    if (node >= N) return;
    int lane = t & 31;
    int beg = off[node], end = off[node + 1];
    float4 acc = bf2f4(*reinterpret_cast<const uint2*>(xb + (size_t)node * D + lane * 4));
    int e = beg;
    for (; e + 2 <= end; e += 2) {
        int s0 = eidx[e], s1 = eidx[e + 1];
        uint2 v0 = *reinterpret_cast<const uint2*>(xb + (size_t)s0 * D + lane * 4);
        uint2 v1 = *reinterpret_cast<const uint2*>(xb + (size_t)s1 * D + lane * 4);
        float4 f0 = bf2f4(v0), f1 = bf2f4(v1);
        acc.x += f0.x + f1.x; acc.y += f0.y + f1.y;
        acc.z += f0.z + f1.z; acc.w += f0.w + f1.w;
    }
    if (e < end) {
        int s0 = eidx[e];
        float4 f0 = bf2f4(*reinterpret_cast<const uint2*>(xb + (size_t)s0 * D + lane * 4));
        acc.x += f0.x; acc.y += f0.y; acc.z += f0.z; acc.w += f0.w;
    }
    uint2 o;
    o.x = (unsigned)f2bf(acc.x) | ((unsigned)f2bf(acc.y) << 16);
    o.y = (unsigned)f2bf(acc.z) | ((unsigned)f2bf(acc.w) << 16);
    *reinterpret_cast<uint2*>(zb + (size_t)node * D + lane * 4) = o;
}

// ---------------------------------------------------- MFMA GEMM1: zb = relu(zb@W1 + b1)
__global__ __launch_bounds__(256) void gemm1_mfma(
        const unsigned short* __restrict__ A, const unsigned short* __restrict__ Wt,
        const float* __restrict__ bias, unsigned short* __restrict__ Out, int N) {
    __shared__ __align__(16) char sW[32768];
    const int tid = threadIdx.x;
    #pragma unroll
    for (int it = 0; it < 8; it++) {
        int idx = tid + it * 256;
        int row = idx >> 4, slot = idx & 15;
        uint4 v = *reinterpret_cast<const uint4*>(Wt + ((size_t)idx << 3));
        *reinterpret_cast<uint4*>(sW + row * 256 + ((slot * 16) ^ ((row & 7) << 4))) = v;
    }
    __syncthreads();

    const int lane = tid & 63, wv = tid >> 6;
    const int r0 = blockIdx.x * 64 + wv * 16;
    int arow = r0 + (lane & 15); if (arow >= N) arow = N - 1;
    const unsigned short* aptr = A + (size_t)arow * D + ((lane >> 4) << 3);

    f32x4 acc[8];
    #pragma unroll
    for (int ct = 0; ct < 8; ct++) {
        float b = bias[ct * 16 + (lane & 15)];
        acc[ct] = (f32x4){b, b, b, b};
    }
    #pragma unroll
    for (int ks = 0; ks < 4; ks++) {
        short8 a = *reinterpret_cast<const short8*>(aptr + ks * 32);
        #pragma unroll
        for (int ct = 0; ct < 8; ct++) {
            int rr = ct * 16 + (lane & 15);
            int kb = ks * 64 + ((lane >> 4) << 4);
            short8 bfr = *reinterpret_cast<const short8*>(sW + rr * 256 + (kb ^ ((rr & 7) << 4)));
            acc[ct] = __builtin_amdgcn_mfma_f32_16x16x32_bf16(a, bfr, acc[ct], 0, 0, 0);
        }
    }
    #pragma unroll
    for (int ct = 0; ct < 8; ct++) {
        #pragma unroll
        for (int r = 0; r < 4; r++) {
            int row = r0 + ((lane >> 4) << 2) + r;
            if (row < N)
                Out[(size_t)row * D + ct * 16 + (lane & 15)] = f2bf(fmaxf(acc[ct][r], 0.f));
        }
    }
}

// ----------------------- MFMA GEMM2: y = zb@W2 + b2 (fp32 out) + column stats
__global__ __launch_bounds__(256) void gemm2_mfma(
        const unsigned short* __restrict__ A, const unsigned short* __restrict__ Wt,
        const float* __restrict__ bias, float* __restrict__ Out,
        float* __restrict__ gstats, int N) {
    __shared__ __align__(16) char sW[32768];
    __shared__ float sStat[2 * D];
    const int tid = threadIdx.x;
    if (tid < 2 * D) sStat[tid] = 0.f;
    #pragma unroll
    for (int it = 0; it < 8; it++) {
        int idx = tid + it * 256;
        int row = idx >> 4, slot = idx & 15;
        uint4 v = *reinterpret_cast<const uint4*>(Wt + ((size_t)idx << 3));
        *reinterpret_cast<uint4*>(sW + row * 256 + ((slot * 16) ^ ((row & 7) << 4))) = v;
    }
    __syncthreads();

    const int lane = tid & 63, wv = tid >> 6;
    const int r0 = blockIdx.x * 64 + wv * 16;
    int arow = r0 + (lane & 15); if (arow >= N) arow = N - 1;
    const unsigned short* aptr = A + (size_t)arow * D + ((lane >> 4) << 3);

    f32x4 acc[8];
    #pragma unroll
    for (int ct = 0; ct < 8; ct++) {
        float b = bias[ct * 16 + (lane & 15)];
        acc[ct] = (f32x4){b, b, b, b};
    }
    #pragma unroll
    for (int ks = 0; ks < 4; ks++) {
        short8 a = *reinterpret_cast<const short8*>(aptr + ks * 32);
        #pragma unroll
        for (int ct = 0; ct < 8; ct++) {
            int rr = ct * 16 + (lane & 15);
            int kb = ks * 64 + ((lane >> 4) << 4);
            short8 bfr = *reinterpret_cast<const short8*>(sW + rr * 256 + (kb ^ ((rr & 7) << 4)));
            acc[ct] = __builtin_amdgcn_mfma_f32_16x16x32_bf16(a, bfr, acc[ct], 0, 0, 0);
        }
    }
    #pragma unroll
    for (int ct = 0; ct < 8; ct++) {
        float s = 0.f, q = 0.f;
        #pragma unroll
        for (int r = 0; r < 4; r++) {
            int row = r0 + ((lane >> 4) << 2) + r;
            float v = acc[ct][r];
            if (row < N) {
                Out[(size_t)row * D + ct * 16 + (lane & 15)] = v;
                s += v; q += v * v;
            }
        }
        s += __shfl_xor(s, 16); q += __shfl_xor(q, 16);
        s += __shfl_xor(s, 32); q += __shfl_xor(q, 32);
        if (lane < 16) {
            atomicAdd(&sStat[ct * 16 + lane], s);
            atomicAdd(&sStat[D + ct * 16 + lane], q);
        }
    }
    __syncthreads();
    if (tid < 2 * D) atomicAdd(&gstats[tid], sStat[tid]);
}

// ---------------- BN (training stats) + ReLU, in place; also emit bf16 copy
__global__ void bn_relu_bf(float* __restrict__ y, unsigned short* __restrict__ xb,
                           const float* __restrict__ stats,
                           const float* __restrict__ gamma, const float* __restrict__ beta,
                           int N) {
    int i = blockIdx.x * blockDim.x + threadIdx.x;
    int n4 = N * D / 4;
    if (i >= n4) return;
    int c0 = (i << 2) & (D - 1);
    float4 v = reinterpret_cast<float4*>(y)[i];
    float o[4] = {v.x, v.y, v.z, v.w};
    float invN = 1.0f / (float)N;
    #pragma unroll
    for (int j = 0; j < 4; j++) {
        int c = c0 + j;
        float mean = stats[c] * invN;
        float var  = stats[D + c] * invN - mean * mean;
        float sc = rsqrtf(var + BN_EPS) * gamma[c];
        float t = (o[j] - mean) * sc + beta[c];
        o[j] = fmaxf(t, 0.f);
    }
    float4 r; r.x = o[0]; r.y = o[1]; r.z = o[2]; r.w = o[3];
    reinterpret_cast<float4*>(y)[i] = r;
    uint2 ob;
    ob.x = (unsigned)f2bf(o[0]) | ((unsigned)f2bf(o[1]) << 16);
    ob.y = (unsigned)f2bf(o[2]) | ((unsigned)f2bf(o[3]) << 16);
    reinterpret_cast<uint2*>(xb)[i] = ob;
}

extern "C" void kernel_launch(void* const* d_in, const int* in_sizes, int n_in,
                              void* d_out, int out_size, void* d_ws, size_t ws_size,
                              hipStream_t stream) {
    const float* h     = (const float*)d_in[0];
    const int*   ei    = (const int*)d_in[1];
    const float* W1    = (const float*)d_in[2];
    const float* b1    = (const float*)d_in[3];
    const float* W2    = (const float*)d_in[4];
    const float* b2    = (const float*)d_in[5];
    const float* gamma = (const float*)d_in[6];
    const float* beta  = (const float*)d_in[7];
    float* out = (float*)d_out;

    const int N = in_sizes[0] / D;
    const int E = in_sizes[1] / 2;
    const int L = in_sizes[2] / (D * D);
    const int nb = (N + 255) / 256;

    // workspace layout
    unsigned short* zb  = (unsigned short*)d_ws;              // N*D bf16
    unsigned short* xb  = zb + (size_t)N * D;                 // N*D bf16
    unsigned short* Wt  = xb + (size_t)N * D;                 // 2L*128*128 bf16
    float* stats = (float*)(Wt + (size_t)2 * L * D * D);      // L*2*D floats
    int* cnt      = (int*)(stats + (size_t)L * 2 * D);
    int* off      = cnt + N;
    int* cursor   = off + N + 1;
    int* bsum     = cursor + N;
    int* blockOff = bsum + nb;
    int* eidx     = blockOff + nb;

    const int* src = ei;
    const int* dst = ei + E;

    const int n4 = N * D / 4;
    const int n8 = N * D / 8;
    const int ewBlocks = (E + 255) / 256;
    const int gatherBlocks = (N * 32 + 255) / 256;
    const int gemmBlocks = (N + 63) / 64;
    const int bnBlocks = (n4 + 255) / 256;
    const int wprepBlocks = (2 * L * D * D) / 256;

    hipMemsetAsync(cnt, 0, N * sizeof(int), stream);
    hipMemsetAsync(stats, 0, (size_t)L * 2 * D * sizeof(float), stream);
    wprep<<<wprepBlocks, 256, 0, stream>>>(W1, W2, Wt, L);
    x2bf<<<(n8 + 255) / 256, 256, 0, stream>>>(h, xb, n8);

    // ---- CSR build
    hist_dst<<<ewBlocks, 256, 0, stream>>>(dst, cnt, E);
    reduce_cnt<<<nb, 256, 0, stream>>>(cnt, bsum, N);
    scan_bsums<<<1, 256, 0, stream>>>(bsum, blockOff, off + N, nb);
    scan_partial<<<nb, 256, 0, stream>>>(cnt, off, cursor, blockOff, N);
    fill_csr<<<ewBlocks, 256, 0, stream>>>(src, dst, cursor, eidx, E);

    for (int l = 0; l < L; l++) {
        float* y = out + (size_t)l * N * D;

        gather_bf<<<gatherBlocks, 256, 0, stream>>>(xb, off, eidx, zb, N);
        gemm1_mfma<<<gemmBlocks, 256, 0, stream>>>(zb, Wt + (size_t)l * D * D,
                                                   b1 + (size_t)l * D, zb, N);
        gemm2_mfma<<<gemmBlocks, 256, 0, stream>>>(zb, Wt + (size_t)(L + l) * D * D,
                                                   b2 + (size_t)l * D, y, stats + (size_t)l * 2 * D, N);
        bn_relu_bf<<<bnBlocks, 256, 0, stream>>>(y, xb, stats + (size_t)l * 2 * D,
                                                 gamma + (size_t)l * D, beta + (size_t)l * D, N);
    }
}

// Round 6
// 244.203 us; speedup vs baseline: 12.0504x; 1.1321x over previous
//
#include <hip/hip_runtime.h>

#define D 128
#define BN_EPS 1e-5f

typedef __attribute__((ext_vector_type(8))) short short8;
typedef __attribute__((ext_vector_type(4))) float f32x4;

// float -> bf16 bits, round-to-nearest-even
__device__ inline unsigned short f2bf(float f) {
    union { float f; unsigned int u; } v; v.f = f;
    unsigned int u = v.u;
    unsigned int r = (u + 0x7FFFu + ((u >> 16) & 1u)) >> 16;
    return (unsigned short)r;
}

__device__ inline float bfbits2f(unsigned int bits) {
    union { unsigned int u; float f; } v; v.u = bits;
    return v.f;
}

__device__ inline float4 bf2f4(uint2 v) {
    float4 r;
    r.x = bfbits2f(v.x << 16);
    r.y = bfbits2f(v.x & 0xFFFF0000u);
    r.z = bfbits2f(v.y << 16);
    r.w = bfbits2f(v.y & 0xFFFF0000u);
    return r;
}

// ------------------------------- histogram + per-edge rank (coalesced write)
__global__ void hist_rank(const int* __restrict__ dst, int* __restrict__ cnt,
                          int* __restrict__ rank, int E) {
    int e = blockIdx.x * blockDim.x + threadIdx.x;
    if (e >= E) return;
    rank[e] = atomicAdd(&cnt[dst[e]], 1);
}

// -------------------------------------------------- scan phase 1: per-block reduce
__global__ void reduce_cnt(const int* __restrict__ cnt, int* __restrict__ bsum, int n) {
    __shared__ int s[256];
    int tid = threadIdx.x;
    int i = blockIdx.x * 256 + tid;
    s[tid] = (i < n) ? cnt[i] : 0;
    __syncthreads();
    for (int ofs = 128; ofs > 0; ofs >>= 1) {
        if (tid < ofs) s[tid] += s[tid + ofs];
        __syncthreads();
    }
    if (tid == 0) bsum[blockIdx.x] = s[0];
}

// -------------------------------------------------- scan phase 2: scan block sums (1 block)
__global__ void scan_bsums(const int* __restrict__ bsum, int* __restrict__ blockOff,
                           int* __restrict__ offN, int nb) {
    __shared__ int s[256];
    int tid = threadIdx.x;
    int v = (tid < nb) ? bsum[tid] : 0;
    s[tid] = v;
    __syncthreads();
    for (int ofs = 1; ofs < 256; ofs <<= 1) {
        int t = (tid >= ofs) ? s[tid - ofs] : 0;
        __syncthreads();
        s[tid] += t;
        __syncthreads();
    }
    if (tid < nb) blockOff[tid] = s[tid] - v;
    if (tid == nb - 1) *offN = s[tid];
}

// -------------------------------------------------- scan phase 3: per-block scan + offset
__global__ void scan_partial(const int* __restrict__ cnt, int* __restrict__ off,
                             const int* __restrict__ blockOff, int n) {
    __shared__ int s[256];
    int tid = threadIdx.x;
    int i = blockIdx.x * 256 + tid;
    int v = (i < n) ? cnt[i] : 0;
    s[tid] = v;
    __syncthreads();
    for (int ofs = 1; ofs < 256; ofs <<= 1) {
        int t = (tid >= ofs) ? s[tid - ofs] : 0;
        __syncthreads();
        s[tid] += t;
        __syncthreads();
    }
    if (i < n) off[i] = blockOff[blockIdx.x] + s[tid] - v;
}

// -------------------------------------------------- CSR fill (no atomics)
__global__ void fill2(const int* __restrict__ src, const int* __restrict__ dst,
                      const int* __restrict__ rank, const int* __restrict__ off,
                      int* __restrict__ eidx, int E) {
    int e = blockIdx.x * blockDim.x + threadIdx.x;
    if (e >= E) return;
    eidx[off[dst[e]] + rank[e]] = src[e];
}

// ------------------------- weight prep: Wt[m][n][k] = bf16(W[m][k][n]), m = 2L mats
__global__ void wprep(const float* __restrict__ W1, const float* __restrict__ W2,
                      unsigned short* __restrict__ Wt, int L) {
    int idx = blockIdx.x * 256 + threadIdx.x;
    int m = idx >> 14;
    int rem = idx & 16383;
    int c = rem >> 7, k = rem & 127;
    const float* W = (m < L) ? (W1 + (size_t)m * D * D) : (W2 + (size_t)(m - L) * D * D);
    Wt[(size_t)m * D * D + c * D + k] = f2bf(W[k * D + c]);
}

// -------------------------------------------------- h (fp32) -> xb (bf16)
__global__ void x2bf(const float* __restrict__ x, unsigned short* __restrict__ xb, int n8) {
    int i = blockIdx.x * 256 + threadIdx.x;
    if (i >= n8) return;
    float4 a = reinterpret_cast<const float4*>(x)[2 * i];
    float4 b = reinterpret_cast<const float4*>(x)[2 * i + 1];
    uint4 o;
    o.x = (unsigned)f2bf(a.x) | ((unsigned)f2bf(a.y) << 16);
    o.y = (unsigned)f2bf(a.z) | ((unsigned)f2bf(a.w) << 16);
    o.z = (unsigned)f2bf(b.x) | ((unsigned)f2bf(b.y) << 16);
    o.w = (unsigned)f2bf(b.z) | ((unsigned)f2bf(b.w) << 16);
    reinterpret_cast<uint4*>(xb)[i] = o;
}

// ------------------------------ z_i = x_i + sum_{j in N(i)} x_j, bf16 in / bf16 out
__global__ __launch_bounds__(256) void gather_bf(
        const unsigned short* __restrict__ xb, const int* __restrict__ off,
        const int* __restrict__ eidx, unsigned short* __restrict__ zb, int N) {
    int t = blockIdx.x * blockDim.x + threadIdx.x;
    int node = t >> 5;
    if (node >= N) return;
    int lane = t & 31;
    int beg = off[node], end = off[node + 1];
    float4 acc = bf2f4(*reinterpret_cast<const uint2*>(xb + (size_t)node * D + lane * 4));
    int e = beg;
    for (; e + 2 <= end; e += 2) {
        int s0 = eidx[e], s1 = eidx[e + 1];
        uint2 v0 = *reinterpret_cast<const uint2*>(xb + (size_t)s0 * D + lane * 4);
        uint2 v1 = *reinterpret_cast<const uint2*>(xb + (size_t)s1 * D + lane * 4);
        float4 f0 = bf2f4(v0), f1 = bf2f4(v1);
        acc.x += f0.x + f1.x; acc.y += f0.y + f1.y;
        acc.z += f0.z + f1.z; acc.w += f0.w + f1.w;
    }
    if (e < end) {
        int s0 = eidx[e];
        float4 f0 = bf2f4(*reinterpret_cast<const uint2*>(xb + (size_t)s0 * D + lane * 4));
        acc.x += f0.x; acc.y += f0.y; acc.z += f0.z; acc.w += f0.w;
    }
    uint2 o;
    o.x = (unsigned)f2bf(acc.x) | ((unsigned)f2bf(acc.y) << 16);
    o.y = (unsigned)f2bf(acc.z) | ((unsigned)f2bf(acc.w) << 16);
    *reinterpret_cast<uint2*>(zb + (size_t)node * D + lane * 4) = o;
}

// ------------- MFMA GEMM1, no LDS: zb = relu(zb@W1 + b1), 128 rows/block,
// 4 waves x 2 row-tiles; B-fragments stream from L2 (Wt is 32KB, grid-broadcast).
__global__ __launch_bounds__(256) void gemm1_mfma(
        const unsigned short* __restrict__ A, const unsigned short* __restrict__ Wt,
        const float* __restrict__ bias, unsigned short* __restrict__ Out, int N) {
    const int tid = threadIdx.x;
    const int lane = tid & 63, wv = tid >> 6;
    const int r0 = blockIdx.x * 128 + wv * 32;
    const int koff = (lane >> 4) << 3;          // 8-elem k-chunk within 32-k slice
    const int col = lane & 15;

    int ar0 = r0 + col;       if (ar0 >= N) ar0 = N - 1;
    int ar1 = r0 + 16 + col;  if (ar1 >= N) ar1 = N - 1;
    const unsigned short* ap0 = A + (size_t)ar0 * D + koff;
    const unsigned short* ap1 = A + (size_t)ar1 * D + koff;
    const unsigned short* wp  = Wt + (size_t)col * D + koff;

    f32x4 acc[2][8];
    #pragma unroll
    for (int ct = 0; ct < 8; ct++) {
        float b = bias[ct * 16 + col];
        acc[0][ct] = (f32x4){b, b, b, b};
        acc[1][ct] = (f32x4){b, b, b, b};
    }
    #pragma unroll
    for (int ks = 0; ks < 4; ks++) {
        short8 a0 = *reinterpret_cast<const short8*>(ap0 + ks * 32);
        short8 a1 = *reinterpret_cast<const short8*>(ap1 + ks * 32);
        #pragma unroll
        for (int ct = 0; ct < 8; ct++) {
            short8 bfr = *reinterpret_cast<const short8*>(wp + (size_t)ct * 16 * D + ks * 32);
            acc[0][ct] = __builtin_amdgcn_mfma_f32_16x16x32_bf16(a0, bfr, acc[0][ct], 0, 0, 0);
            acc[1][ct] = __builtin_amdgcn_mfma_f32_16x16x32_bf16(a1, bfr, acc[1][ct], 0, 0, 0);
        }
    }
    #pragma unroll
    for (int t = 0; t < 2; t++) {
        #pragma unroll
        for (int ct = 0; ct < 8; ct++) {
            #pragma unroll
            for (int r = 0; r < 4; r++) {
                int row = r0 + t * 16 + ((lane >> 4) << 2) + r;
                if (row < N)
                    Out[(size_t)row * D + ct * 16 + col] = f2bf(fmaxf(acc[t][ct][r], 0.f));
            }
        }
    }
}

// ------------- MFMA GEMM2, no LDS: y = zb@W2 + b2 (fp32 out) + column stats
__global__ __launch_bounds__(256) void gemm2_mfma(
        const unsigned short* __restrict__ A, const unsigned short* __restrict__ Wt,
        const float* __restrict__ bias, float* __restrict__ Out,
        float* __restrict__ gstats, int N) {
    __shared__ float sStat[2 * D];
    const int tid = threadIdx.x;
    if (tid < 2 * D) sStat[tid] = 0.f;
    __syncthreads();

    const int lane = tid & 63, wv = tid >> 6;
    const int r0 = blockIdx.x * 128 + wv * 32;
    const int koff = (lane >> 4) << 3;
    const int col = lane & 15;

    int ar0 = r0 + col;       if (ar0 >= N) ar0 = N - 1;
    int ar1 = r0 + 16 + col;  if (ar1 >= N) ar1 = N - 1;
    const unsigned short* ap0 = A + (size_t)ar0 * D + koff;
    const unsigned short* ap1 = A + (size_t)ar1 * D + koff;
    const unsigned short* wp  = Wt + (size_t)col * D + koff;

    f32x4 acc[2][8];
    #pragma unroll
    for (int ct = 0; ct < 8; ct++) {
        float b = bias[ct * 16 + col];
        acc[0][ct] = (f32x4){b, b, b, b};
        acc[1][ct] = (f32x4){b, b, b, b};
    }
    #pragma unroll
    for (int ks = 0; ks < 4; ks++) {
        short8 a0 = *reinterpret_cast<const short8*>(ap0 + ks * 32);
        short8 a1 = *reinterpret_cast<const short8*>(ap1 + ks * 32);
        #pragma unroll
        for (int ct = 0; ct < 8; ct++) {
            short8 bfr = *reinterpret_cast<const short8*>(wp + (size_t)ct * 16 * D + ks * 32);
            acc[0][ct] = __builtin_amdgcn_mfma_f32_16x16x32_bf16(a0, bfr, acc[0][ct], 0, 0, 0);
            acc[1][ct] = __builtin_amdgcn_mfma_f32_16x16x32_bf16(a1, bfr, acc[1][ct], 0, 0, 0);
        }
    }
    #pragma unroll
    for (int ct = 0; ct < 8; ct++) {
        float s = 0.f, q = 0.f;
        #pragma unroll
        for (int t = 0; t < 2; t++) {
            #pragma unroll
            for (int r = 0; r < 4; r++) {
                int row = r0 + t * 16 + ((lane >> 4) << 2) + r;
                float v = acc[t][ct][r];
                if (row < N) {
                    Out[(size_t)row * D + ct * 16 + col] = v;
                    s += v; q += v * v;
                }
            }
        }
        s += __shfl_xor(s, 16); q += __shfl_xor(q, 16);
        s += __shfl_xor(s, 32); q += __shfl_xor(q, 32);
        if (lane < 16) {
            atomicAdd(&sStat[ct * 16 + lane], s);
            atomicAdd(&sStat[D + ct * 16 + lane], q);
        }
    }
    __syncthreads();
    if (tid < 2 * D) atomicAdd(&gstats[tid], sStat[tid]);
}

// ---------------- BN (training stats) + ReLU, in place; also emit bf16 copy
__global__ void bn_relu_bf(float* __restrict__ y, unsigned short* __restrict__ xb,
                           const float* __restrict__ stats,
                           const float* __restrict__ gamma, const float* __restrict__ beta,
                           int N) {
    int i = blockIdx.x * blockDim.x + threadIdx.x;
    int n4 = N * D / 4;
    if (i >= n4) return;
    int c0 = (i << 2) & (D - 1);
    float4 v = reinterpret_cast<float4*>(y)[i];
    float o[4] = {v.x, v.y, v.z, v.w};
    float invN = 1.0f / (float)N;
    #pragma unroll
    for (int j = 0; j < 4; j++) {
        int c = c0 + j;
        float mean = stats[c] * invN;
        float var  = stats[D + c] * invN - mean * mean;
        float sc = rsqrtf(var + BN_EPS) * gamma[c];
        float t = (o[j] - mean) * sc + beta[c];
        o[j] = fmaxf(t, 0.f);
    }
    float4 r; r.x = o[0]; r.y = o[1]; r.z = o[2]; r.w = o[3];
    reinterpret_cast<float4*>(y)[i] = r;
    uint2 ob;
    ob.x = (unsigned)f2bf(o[0]) | ((unsigned)f2bf(o[1]) << 16);
    ob.y = (unsigned)f2bf(o[2]) | ((unsigned)f2bf(o[3]) << 16);
    reinterpret_cast<uint2*>(xb)[i] = ob;
}

extern "C" void kernel_launch(void* const* d_in, const int* in_sizes, int n_in,
                              void* d_out, int out_size, void* d_ws, size_t ws_size,
                              hipStream_t stream) {
    const float* h     = (const float*)d_in[0];
    const int*   ei    = (const int*)d_in[1];
    const float* W1    = (const float*)d_in[2];
    const float* b1    = (const float*)d_in[3];
    const float* W2    = (const float*)d_in[4];
    const float* b2    = (const float*)d_in[5];
    const float* gamma = (const float*)d_in[6];
    const float* beta  = (const float*)d_in[7];
    float* out = (float*)d_out;

    const int N = in_sizes[0] / D;
    const int E = in_sizes[1] / 2;
    const int L = in_sizes[2] / (D * D);
    const int nb = (N + 255) / 256;

    // workspace layout
    unsigned short* zb  = (unsigned short*)d_ws;              // N*D bf16
    unsigned short* xb  = zb + (size_t)N * D;                 // N*D bf16
    unsigned short* Wt  = xb + (size_t)N * D;                 // 2L*128*128 bf16
    float* stats = (float*)(Wt + (size_t)2 * L * D * D);      // L*2*D floats
    int* cnt      = (int*)(stats + (size_t)L * 2 * D);        // N ints
    int* off      = cnt + N;                                  // N+1 ints
    int* bsum     = off + N + 1;                              // nb ints
    int* blockOff = bsum + nb;                                // nb ints
    int* rank     = blockOff + nb;                            // E ints
    int* eidx     = rank + E;                                 // E ints

    const int* src = ei;
    const int* dst = ei + E;

    const int n4 = N * D / 4;
    const int n8 = N * D / 8;
    const int ewBlocks = (E + 255) / 256;
    const int gatherBlocks = (N * 32 + 255) / 256;
    const int gemmBlocks = (N + 127) / 128;
    const int bnBlocks = (n4 + 255) / 256;
    const int wprepBlocks = (2 * L * D * D) / 256;

    hipMemsetAsync(cnt, 0, N * sizeof(int), stream);
    hipMemsetAsync(stats, 0, (size_t)L * 2 * D * sizeof(float), stream);
    wprep<<<wprepBlocks, 256, 0, stream>>>(W1, W2, Wt, L);
    x2bf<<<(n8 + 255) / 256, 256, 0, stream>>>(h, xb, n8);

    // ---- CSR build (rank-based, atomic-free permute)
    hist_rank<<<ewBlocks, 256, 0, stream>>>(dst, cnt, rank, E);
    reduce_cnt<<<nb, 256, 0, stream>>>(cnt, bsum, N);
    scan_bsums<<<1, 256, 0, stream>>>(bsum, blockOff, off + N, nb);
    scan_partial<<<nb, 256, 0, stream>>>(cnt, off, blockOff, N);
    fill2<<<ewBlocks, 256, 0, stream>>>(src, dst, rank, off, eidx, E);

    for (int l = 0; l < L; l++) {
        float* y = out + (size_t)l * N * D;

        gather_bf<<<gatherBlocks, 256, 0, stream>>>(xb, off, eidx, zb, N);
        gemm1_mfma<<<gemmBlocks, 256, 0, stream>>>(zb, Wt + (size_t)l * D * D,
                                                   b1 + (size_t)l * D, zb, N);
        gemm2_mfma<<<gemmBlocks, 256, 0, stream>>>(zb, Wt + (size_t)(L + l) * D * D,
                                                   b2 + (size_t)l * D, y, stats + (size_t)l * 2 * D, N);
        bn_relu_bf<<<bnBlocks, 256, 0, stream>>>(y, xb, stats + (size_t)l * 2 * D,
                                                 gamma + (size_t)l * D, beta + (size_t)l * D, N);
    }
}